// Round 7
// baseline (773.510 us; speedup 1.0000x reference)
//
#include <hip/hip_runtime.h>
#include <hip/hip_bf16.h>
#include <stdint.h>

// ---------------------------------------------------------------------------
// SmallTransformerBlock on MI355X (gfx950)  — Round 7
//   B=4, T=2048, D=1024, FF=4096, full-D attention, scale = sqrt(128)
// R6 -> R7 changes:
//   * B operand bypasses LDS: fragments loaded per-lane straight from global
//     (16 B/lane, 4 kq-lanes share one 64 B segment; wc-partner wave hits L1).
//     Halves LDS traffic (the R6 binding constraint: 64 KB frag reads +
//     32 KB stage writes per block-iter ~ 1540 cyc vs MFMA 620).
//   * oproj / FFN2 outputs bf16 (t0, y); LayerNorms read bf16 (saves ~64 MB).
// ---------------------------------------------------------------------------

typedef __bf16 bf16x8 __attribute__((ext_vector_type(8)));
typedef float f32x4 __attribute__((ext_vector_type(4)));

__device__ __forceinline__ unsigned short f2b(float f) {
    __hip_bfloat16 h = __float2bfloat16(f);
    unsigned short u;
    __builtin_memcpy(&u, &h, 2);
    return u;
}

__device__ __forceinline__ float b2f(unsigned short u) {
    __hip_bfloat16 h;
    __builtin_memcpy(&h, &u, 2);
    return __bfloat162float(h);
}

__device__ __forceinline__ void async_copy16(const unsigned short* g, unsigned short* l) {
    __builtin_amdgcn_global_load_lds((__attribute__((address_space(1))) void*)(g),
                                     (__attribute__((address_space(3))) void*)(l),
                                     16, 0, 0);
}

// ---------------------------------------------------------------------------
// GEMM:  C[M,N] = A[M,K] @ Bt[N,K]^T   (A, Bt bf16 raw ushort, K-contiguous)
// A staged through LDS (global_load_lds, XOR swizzle); B loaded per-lane
// direct from global into registers. All outputs bf16.
// MODE 0: +bias                  (fused QKV)
// MODE 1: exp(acc*scale - 16)    (scores -> unnormalized P)
// MODE 2: *rowinv[z*sR + row]    (ctx = P @ V, normalized)
// MODE 3: +bias, +resid(bf16)    (o-proj, FFN2)
// MODE 4: +bias, relu            (FFN1)
// Tile 128x128, BK=64. grid = (N/128, M/128, batch), block = 256. K%64==0.
// ---------------------------------------------------------------------------
template <int MODE>
__launch_bounds__(256, 2)
__global__ void gemm_bt(const unsigned short* __restrict__ A, int lda,
                        const unsigned short* __restrict__ Bt, int ldb,
                        unsigned short* __restrict__ Cv, int ldc,
                        const float* __restrict__ bias,
                        const unsigned short* __restrict__ resid, int ldr,
                        const float* __restrict__ rowinv,
                        int M, int N, int K,
                        long sA, long sB, long sC, long sR, float scale) {
    constexpr bool HAS_BIAS  = (MODE == 0 || MODE == 3 || MODE == 4);
    constexpr bool HAS_RESID = (MODE == 3);
    constexpr bool RELU      = (MODE == 4);
    constexpr bool EXPW      = (MODE == 1);
    constexpr bool ROWSCALE  = (MODE == 2);

    __shared__ unsigned short ldsA[8192];  // A tile [128][64]

    // ---- XCD-aware swizzle: round-robin dispatch puts block n on XCD n%8.
    const int nx = (int)gridDim.x, ny = (int)gridDim.y;
    int bx, by;
    if ((ny & 7) == 0) {
        const int n     = (int)blockIdx.y * nx + (int)blockIdx.x;
        const int xcd   = n & 7;
        const int slot  = n >> 3;
        const int bandh = ny >> 3;
        by = xcd * bandh + (slot % bandh);
        bx = slot / bandh;
    } else {
        bx = (int)blockIdx.x;
        by = (int)blockIdx.y;
    }

    const int z = blockIdx.z;
    const unsigned short* Ab = A + (long)z * sA + (long)by * 128 * lda;
    const unsigned short* Bb = Bt + (long)z * sB + (long)bx * 128 * ldb;

    const int tid  = threadIdx.x;
    const int lane = tid & 63;
    const int wid  = tid >> 6;
    const int wr   = wid >> 1;   // wave row (0..1) -> 64 rows
    const int wc   = wid & 1;    // wave col (0..1) -> 64 cols

    f32x4 acc[4][4] = {};

    // A staging: tile is 1024 16B-chunks; slot s holds global
    // (row = s>>3, logical chunk = (s&7) ^ ((s>>3)&7))  [XOR swizzle].
    long offA[4];
    unsigned short* dA[4];
#pragma unroll
    for (int p = 0; p < 4; ++p) {
        const int s = p * 256 + tid;
        const int r = s >> 3;
        const int c = ((s & 7) ^ (r & 7)) * 8;
        offA[p] = (long)r * lda + c;
        dA[p] = ldsA + (p * 256 + wid * 64) * 8;
    }

    const int kq = lane >> 4;    // k-chunk within 32-k step (0..3)
    const int rr = lane & 15;    // row/col within 16-slice
    const int st0 = kq ^ (rr & 7);
    const int st1 = (4 + kq) ^ (rr & 7);

    // B direct-load pointers: lane's col row in Bt, kq chunk folded in.
    const unsigned short* Bl[4];
#pragma unroll
    for (int ni = 0; ni < 4; ++ni)
        Bl[ni] = Bb + (long)(wc * 64 + ni * 16 + rr) * ldb + kq * 8;

    for (int k0 = 0; k0 < K; k0 += 64) {
        __syncthreads();
#pragma unroll
        for (int p = 0; p < 4; ++p) async_copy16(Ab + offA[p] + k0, dA[p]);
        // B fragments for both 32-k halves: global -> regs (no LDS).
        bf16x8 bre[2][4];
#pragma unroll
        for (int ks = 0; ks < 2; ++ks)
#pragma unroll
            for (int ni = 0; ni < 4; ++ni)
                bre[ks][ni] = *(const bf16x8*)(Bl[ni] + k0 + ks * 32);
        __syncthreads();

#pragma unroll
        for (int ks = 0; ks < 2; ++ks) {
            const int st = ks ? st1 : st0;
            bf16x8 af[4];
#pragma unroll
            for (int mi = 0; mi < 4; ++mi)
                af[mi] = *(const bf16x8*)(ldsA + (wr * 64 + mi * 16 + rr) * 64 + st * 8);
#pragma unroll
            for (int mi = 0; mi < 4; ++mi)
#pragma unroll
                for (int ni = 0; ni < 4; ++ni)
                    acc[mi][ni] = __builtin_amdgcn_mfma_f32_16x16x32_bf16(af[mi], bre[ks][ni], acc[mi][ni], 0, 0, 0);
        }
    }

    // Epilogue. C/D layout: col = lane&15, row = (lane>>4)*4 + reg  (m89/m91)
    const long zC = (long)z * sC;
    const int colb = bx * 128 + wc * 64 + rr;
    const int rowb = by * 128 + wr * 64 + kq * 4;
#pragma unroll
    for (int mi = 0; mi < 4; ++mi) {
#pragma unroll
        for (int ni = 0; ni < 4; ++ni) {
            const int col = colb + ni * 16;
            float bv = 0.0f;
            if constexpr (HAS_BIAS) bv = bias[col];
#pragma unroll
            for (int r = 0; r < 4; ++r) {
                const int row = rowb + mi * 16 + r;
                float v = acc[mi][ni][r] * scale + bv;
                if constexpr (EXPW) v = __expf(v - 16.0f);
                if constexpr (ROWSCALE) v *= rowinv[(long)z * sR + row];
                if constexpr (HAS_RESID) v += b2f(resid[(long)z * sR + (long)row * ldr + col]);
                if constexpr (RELU) v = v > 0.0f ? v : 0.0f;
                Cv[zC + (long)row * ldc + col] = f2b(v);
            }
        }
    }
}

// --------------------------- cast f32 -> bf16 ------------------------------
__global__ void cast_f32_bf16(const float* __restrict__ in, unsigned short* __restrict__ out, long n) {
    long i = ((long)blockIdx.x * 256 + threadIdx.x) * 4;
    if (i >= n) return;
    float4 v = *(const float4*)(in + i);
    ushort4 o;
    o.x = f2b(v.x); o.y = f2b(v.y); o.z = f2b(v.z); o.w = f2b(v.w);
    *(ushort4*)(out + i) = o;
}

// --------------------------- concat 3 bias vectors -------------------------
__global__ void concat3(const float* __restrict__ a, const float* __restrict__ b,
                        const float* __restrict__ c, float* __restrict__ o, int n) {
    int i = blockIdx.x * 256 + threadIdx.x;
    if (i < n) { o[i] = a[i]; o[i + n] = b[i]; o[i + 2 * n] = c[i]; }
}

// ------------------- transpose + cast f32[R][C] -> bf16[C][R] --------------
__global__ void transpose_cast(const float* __restrict__ src, unsigned short* __restrict__ dst,
                               int R, int C) {
    __shared__ float tile[32][33];
    const int bx = blockIdx.x * 32;  // col base in src
    const int by = blockIdx.y * 32;  // row base in src
    const int tx = threadIdx.x, ty = threadIdx.y;
#pragma unroll
    for (int i = 0; i < 32; i += 8)
        tile[ty + i][tx] = src[(long)(by + ty + i) * C + bx + tx];
    __syncthreads();
#pragma unroll
    for (int i = 0; i < 32; i += 8)
        dst[(long)(bx + ty + i) * R + by + tx] = f2b(tile[tx][ty + i]);
}

// ------ batched: 4 square f32[N][N] -> bf16[N][N]^T, dst contiguous --------
__global__ void transpose_cast4(const float* __restrict__ s0, const float* __restrict__ s1,
                                const float* __restrict__ s2, const float* __restrict__ s3,
                                unsigned short* __restrict__ dst, int N) {
    const float* src = (blockIdx.z == 0) ? s0 : (blockIdx.z == 1) ? s1 : (blockIdx.z == 2) ? s2 : s3;
    unsigned short* d = dst + (long)blockIdx.z * N * N;
    __shared__ float tile[32][33];
    const int bx = blockIdx.x * 32;
    const int by = blockIdx.y * 32;
    const int tx = threadIdx.x, ty = threadIdx.y;
#pragma unroll
    for (int i = 0; i < 32; i += 8)
        tile[ty + i][tx] = src[(long)(by + ty + i) * N + bx + tx];
    __syncthreads();
#pragma unroll
    for (int i = 0; i < 32; i += 8)
        d[(long)(bx + ty + i) * N + by + tx] = f2b(tile[tx][ty + i]);
}

// -------- transpose bf16 [R][C] (row stride ld) -> [C][R], batched ---------
__global__ void transpose_bf16(const unsigned short* __restrict__ src, long sS, int ld,
                               unsigned short* __restrict__ dst, long sD, int R, int C) {
    const int z = blockIdx.z;
    src += (long)z * sS;
    dst += (long)z * sD;
    __shared__ unsigned short tile[32][33];
    const int bx = blockIdx.x * 32;  // col base
    const int by = blockIdx.y * 32;  // row base
    const int tx = threadIdx.x, ty = threadIdx.y;
#pragma unroll
    for (int i = 0; i < 32; i += 8)
        tile[ty + i][tx] = src[(long)(by + ty + i) * ld + bx + tx];
    __syncthreads();
#pragma unroll
    for (int i = 0; i < 32; i += 8)
        dst[(long)(bx + ty + i) * R + by + tx] = tile[tx][ty + i];
}

// ---- rowsum of bf16 matrix rows (2048 cols) -> 1/sum (fp32) per row -------
__global__ void rowsum_inv(const unsigned short* __restrict__ P, float* __restrict__ inv) {
    const long row = blockIdx.x;
    const ushort4* pr = (const ushort4*)(P + row * 2048);
    const int t = threadIdx.x;
    ushort4 a = pr[t];
    ushort4 b = pr[t + 256];
    float s = b2f(a.x) + b2f(a.y) + b2f(a.z) + b2f(a.w)
            + b2f(b.x) + b2f(b.y) + b2f(b.z) + b2f(b.w);
#pragma unroll
    for (int off = 32; off > 0; off >>= 1) s += __shfl_down(s, off);
    __shared__ float red[4];
    if ((t & 63) == 0) red[t >> 6] = s;
    __syncthreads();
    if (t == 0) inv[row] = 1.0f / (red[0] + red[1] + red[2] + red[3]);
}

// ------------------ LayerNorm (1024 cols), bf16 input ----------------------
template <bool OUT_F32>
__global__ void layernorm_bf16(const unsigned short* __restrict__ in, float* outf,
                               unsigned short* outb,
                               const float* __restrict__ g, const float* __restrict__ b) {
    const long row = blockIdx.x;
    const int t = threadIdx.x;
    const ushort4 u = ((const ushort4*)(in + row * 1024))[t];
    float4 v;
    v.x = b2f(u.x); v.y = b2f(u.y); v.z = b2f(u.z); v.w = b2f(u.w);
    float s = v.x + v.y + v.z + v.w;
    float q = v.x * v.x + v.y * v.y + v.z * v.z + v.w * v.w;
#pragma unroll
    for (int off = 32; off > 0; off >>= 1) {
        s += __shfl_down(s, off);
        q += __shfl_down(q, off);
    }
    __shared__ float red[8];
    if ((t & 63) == 0) { red[t >> 6] = s; red[4 + (t >> 6)] = q; }
    __syncthreads();
    s = red[0] + red[1] + red[2] + red[3];
    q = red[4] + red[5] + red[6] + red[7];
    const float mean = s * (1.0f / 1024.0f);
    const float var  = q * (1.0f / 1024.0f) - mean * mean;
    const float inv  = rsqrtf(var + 1e-5f);
    const float4 gg = ((const float4*)g)[t];
    const float4 bb = ((const float4*)b)[t];
    float4 o;
    o.x = (v.x - mean) * inv * gg.x + bb.x;
    o.y = (v.y - mean) * inv * gg.y + bb.y;
    o.z = (v.z - mean) * inv * gg.z + bb.z;
    o.w = (v.w - mean) * inv * gg.w + bb.w;
    if constexpr (OUT_F32) {
        ((float4*)(outf + row * 1024))[t] = o;
    } else {
        ushort4 ob;
        ob.x = f2b(o.x); ob.y = f2b(o.y); ob.z = f2b(o.z); ob.w = f2b(o.w);
        ((ushort4*)(outb + row * 1024))[t] = ob;
    }
}

// ---------------------------------------------------------------------------
extern "C" void kernel_launch(void* const* d_in, const int* in_sizes, int n_in,
                              void* d_out, int out_size, void* d_ws, size_t ws_size,
                              hipStream_t stream) {
    (void)in_sizes; (void)n_in; (void)out_size; (void)ws_size;
    const float* x   = (const float*)d_in[0];
    const float* wq  = (const float*)d_in[1];
    const float* bq  = (const float*)d_in[2];
    const float* wk  = (const float*)d_in[3];
    const float* bk  = (const float*)d_in[4];
    const float* wv  = (const float*)d_in[5];
    const float* bv  = (const float*)d_in[6];
    const float* wo  = (const float*)d_in[7];
    const float* bo  = (const float*)d_in[8];
    const float* w1  = (const float*)d_in[9];
    const float* b1  = (const float*)d_in[10];
    const float* w2  = (const float*)d_in[11];
    const float* b2  = (const float*)d_in[12];
    const float* g1  = (const float*)d_in[13];
    const float* be1 = (const float*)d_in[14];
    const float* g2  = (const float*)d_in[15];
    const float* be2 = (const float*)d_in[16];

    const int D = 1024, FF = 4096, T = 2048, M = 8192;
    const size_t MB = 1ull << 20;
    char* w = (char*)d_ws;
    // Arena (lifetime-aliased):
    unsigned short* wqT = (unsigned short*)(w + 0 * MB);    // [3072][1024] wcat (wq|wk|wv)
    unsigned short* woT = (unsigned short*)(w + 6 * MB);    // [1024][1024]
    unsigned short* w1T = (unsigned short*)(w + 8 * MB);    // [4096][1024]
    unsigned short* w2T = (unsigned short*)(w + 16 * MB);   // [1024][4096]
    unsigned short* xb  = (unsigned short*)(w + 24 * MB);   // [8192][1024] (QKV A + oproj resid)
    unsigned short* qkv = (unsigned short*)(w + 40 * MB);   // [8192][3072], dead after ctx
    float*          rsum = (float*)(w + 40 * MB);           // [8192] — aliases dead q-part after scores
    float*          bcat = (float*)(w + 88 * MB);           // [3072] — dead before vT written
    unsigned short* vT  = (unsigned short*)(w + 88 * MB);   // [4][1024][2048] (16 MiB), dead after ctx
    unsigned short* pr  = (unsigned short*)(w + 104 * MB);  // [4][2048][2048] bf16 (32 MiB), dead after ctx
    unsigned short* ctxb = (unsigned short*)(w + 136 * MB); // [8192][1024] bf16, dead after oproj
    unsigned short* t0  = (unsigned short*)(w + 152 * MB);  // [8192][1024] bf16 (16 MiB), dead after LN1
    unsigned short* x1b = (unsigned short*)(w + 56 * MB);   // [8192][1024] bf16 (FFN1 A + FFN2 resid)
    unsigned short* h   = (unsigned short*)(w + 88 * MB);   // [8192][4096] bf16 (64 MiB), reuse vT/pr/ctxb
    unsigned short* y   = (unsigned short*)(w + 168 * MB);  // [8192][1024] bf16 (16 MiB)

    const dim3 tb(32, 8);
    // weight transposes + casts (wq/wk/wv/wo batched; dst contiguous from wqT)
    transpose_cast4<<<dim3(32, 32, 4), tb, 0, stream>>>(wq, wk, wv, wo, wqT, D);
    transpose_cast<<<dim3(128, 32), tb, 0, stream>>>(w1, w1T, D, FF);
    transpose_cast<<<dim3(32, 128), tb, 0, stream>>>(w2, w2T, FF, D);
    concat3<<<4, 256, 0, stream>>>(bq, bk, bv, bcat, D);
    cast_f32_bf16<<<8192, 256, 0, stream>>>(x, xb, (long)M * D);

    // Fused QKV projection: [8192][3072] = xb @ wcat^T + bcat
    gemm_bt<0><<<dim3(24, 64, 1), 256, 0, stream>>>(xb, D, wqT, D, qkv, 3 * D, bcat, nullptr, 0,
                                                    nullptr, M, 3 * D, D, 0, 0, 0, 0, 1.0f);

    // V transpose per batch: view [2048][1024] (stride 3072) -> [1024][2048]
    transpose_bf16<<<dim3(32, 64, 4), tb, 0, stream>>>(qkv + 2 * D, (long)T * 3 * D, 3 * D,
                                                       vT, (long)D * T, T, D);

    // P = exp(q @ k^T / sqrt(128) - 16), bf16 unnormalized
    gemm_bt<1><<<dim3(16, 16, 4), 256, 0, stream>>>(qkv, 3 * D, qkv + D, 3 * D, pr, T,
                                                    nullptr, nullptr, 0, nullptr, T, T, D,
                                                    (long)T * 3 * D, (long)T * 3 * D, (long)T * T, 0,
                                                    0.08838834764831845f);
    // 1/rowsum (q-part of qkv dead now; rsum aliases it)
    rowsum_inv<<<8192, 256, 0, stream>>>(pr, rsum);

    // ctx = (P @ v) * rowinv
    gemm_bt<2><<<dim3(8, 16, 4), 256, 0, stream>>>(pr, T, vT, T, ctxb, D,
                                                   nullptr, nullptr, 0, rsum, T, D, T,
                                                   (long)T * T, (long)D * T, (long)T * D, T, 1.0f);

    // o-projection + residual (bf16 xb), bf16 out
    gemm_bt<3><<<dim3(8, 64, 1), 256, 0, stream>>>(ctxb, D, woT, D, t0, D, bo, xb, D,
                                                   nullptr, M, D, D, 0, 0, 0, 0, 1.0f);

    // LN1 (bf16 in) -> bf16 x1b (FFN input + FFN2 residual)
    layernorm_bf16<false><<<8192, 256, 0, stream>>>(t0, nullptr, x1b, g1, be1);

    // FFN
    gemm_bt<4><<<dim3(32, 64, 1), 256, 0, stream>>>(x1b, D, w1T, D, h, FF, b1, nullptr, 0,
                                                    nullptr, M, FF, D, 0, 0, 0, 0, 1.0f);
    gemm_bt<3><<<dim3(8, 64, 1), 256, 0, stream>>>(h, FF, w2T, FF, y, D, b2, x1b, D,
                                                   nullptr, M, D, FF, 0, 0, 0, 0, 1.0f);

    // LN2 (bf16 in) -> output (fp32)
    layernorm_bf16<true><<<8192, 256, 0, stream>>>(y, (float*)d_out, nullptr, g2, be2);
}

// Round 8
// 475.653 us; speedup vs baseline: 1.6262x; 1.6262x over previous
//
#include <hip/hip_runtime.h>
#include <hip/hip_bf16.h>
#include <stdint.h>

// ---------------------------------------------------------------------------
// SmallTransformerBlock on MI355X (gfx950)  — Round 8
//   B=4, T=2048, D=1024, FF=4096, full-D attention, scale = sqrt(128)
// R7 -> R8 changes:
//   * REVERT B-direct-load (R7: 773 µs, MfmaUtil 18% — per-lane scattered B
//     reloads every iter with no latency hiding). B back through LDS.
//   * BK=128 K-tiles for the grid-limited GEMMs (ctx/oproj/FFN2: 512 blocks
//     = 2 blocks/CU regardless), halving barrier-drain count at zero
//     occupancy cost (m132's BK=128 loss was occupancy — not applicable
//     here). BK=64 kept where grids are large (QKV/scores/FFN1).
//   * Kept from R7: bf16 outputs for oproj/FFN2, bf16-input LayerNorms.
// ---------------------------------------------------------------------------

typedef __bf16 bf16x8 __attribute__((ext_vector_type(8)));
typedef float f32x4 __attribute__((ext_vector_type(4)));

__device__ __forceinline__ unsigned short f2b(float f) {
    __hip_bfloat16 h = __float2bfloat16(f);
    unsigned short u;
    __builtin_memcpy(&u, &h, 2);
    return u;
}

__device__ __forceinline__ float b2f(unsigned short u) {
    __hip_bfloat16 h;
    __builtin_memcpy(&h, &u, 2);
    return __bfloat162float(h);
}

__device__ __forceinline__ void async_copy16(const unsigned short* g, unsigned short* l) {
    __builtin_amdgcn_global_load_lds((__attribute__((address_space(1))) void*)(g),
                                     (__attribute__((address_space(3))) void*)(l),
                                     16, 0, 0);
}

// ---------------------------------------------------------------------------
// GEMM:  C[M,N] = A[M,K] @ Bt[N,K]^T   (A, Bt bf16 raw ushort, K-contiguous)
// MODE 0: +bias                  (fused QKV)
// MODE 1: exp(acc*scale - 16)    (scores -> unnormalized P)
// MODE 2: *rowinv[z*sR + row]    (ctx = P @ V, normalized)
// MODE 3: +bias, +resid(bf16)    (o-proj, FFN2)
// MODE 4: +bias, relu            (FFN1)
// All outputs bf16. Tile 128x128, BK in {64,128}.
// grid = (N/128, M/128, batch), block = 256.  Requires K % BK == 0.
// ---------------------------------------------------------------------------
template <int MODE, int BK>
__launch_bounds__(256, 2)
__global__ void gemm_bt(const unsigned short* __restrict__ A, int lda,
                        const unsigned short* __restrict__ Bt, int ldb,
                        unsigned short* __restrict__ Cv, int ldc,
                        const float* __restrict__ bias,
                        const unsigned short* __restrict__ resid, int ldr,
                        const float* __restrict__ rowinv,
                        int M, int N, int K,
                        long sA, long sB, long sC, long sR, float scale) {
    constexpr bool HAS_BIAS  = (MODE == 0 || MODE == 3 || MODE == 4);
    constexpr bool HAS_RESID = (MODE == 3);
    constexpr bool RELU      = (MODE == 4);
    constexpr bool EXPW      = (MODE == 1);
    constexpr bool ROWSCALE  = (MODE == 2);
    constexpr int  CPR = BK / 8;    // 16B chunks per row
    constexpr int  P   = BK / 16;   // staging groups of 256 chunks per operand
    constexpr int  KS  = BK / 32;   // 32-k steps per tile

    __shared__ unsigned short lds_us[256 * BK];  // A[128][BK] + B[128][BK]
    unsigned short* ldsA = lds_us;
    unsigned short* ldsB = lds_us + 128 * BK;

    // ---- XCD-aware swizzle: round-robin dispatch puts block n on XCD n%8.
    // Each XCD gets a band of ny/8 A-row-blocks x all B-cols, column-major
    // within the band so B blocks are reused back-to-back in its L2.
    const int nx = (int)gridDim.x, ny = (int)gridDim.y;
    int bx, by;
    if ((ny & 7) == 0) {
        const int n     = (int)blockIdx.y * nx + (int)blockIdx.x;
        const int xcd   = n & 7;
        const int slot  = n >> 3;
        const int bandh = ny >> 3;
        by = xcd * bandh + (slot % bandh);
        bx = slot / bandh;
    } else {
        bx = (int)blockIdx.x;
        by = (int)blockIdx.y;
    }

    const int z = blockIdx.z;
    const unsigned short* Ab = A + (long)z * sA + (long)by * 128 * lda;
    const unsigned short* Bb = Bt + (long)z * sB + (long)bx * 128 * ldb;

    const int tid  = threadIdx.x;
    const int lane = tid & 63;
    const int wid  = tid >> 6;
    const int wr   = wid >> 1;   // wave row (0..1) -> 64 rows
    const int wc   = wid & 1;    // wave col (0..1) -> 64 cols

    f32x4 acc[4][4] = {};

    // Staging: tile is 128*CPR 16B-chunks; slot s holds global
    // (row = s/CPR, logical chunk = (s%CPR) ^ (row%CPR))  [XOR swizzle].
    // LDS dest = wave-uniform base + lane*16 (global_load_lds scatter).
    long offA[P], offB[P];
    unsigned short* dA[P];
    unsigned short* dB[P];
#pragma unroll
    for (int p = 0; p < P; ++p) {
        const int s = p * 256 + tid;
        const int r = s / CPR;
        const int c = ((s & (CPR - 1)) ^ (r & (CPR - 1))) * 8;
        offA[p] = (long)r * lda + c;
        offB[p] = (long)r * ldb + c;
        dA[p] = ldsA + (p * 256 + wid * 64) * 8;
        dB[p] = ldsB + (p * 256 + wid * 64) * 8;
    }

    const int kq = lane >> 4;    // k-chunk within 32-k step (0..3)
    const int rr = lane & 15;    // row within 16-slice

    for (int k0 = 0; k0 < K; k0 += BK) {
        __syncthreads();
#pragma unroll
        for (int p = 0; p < P; ++p) {
            async_copy16(Ab + offA[p] + k0, dA[p]);
            async_copy16(Bb + offB[p] + k0, dB[p]);
        }
        __syncthreads();

#pragma unroll
        for (int ks = 0; ks < KS; ++ks) {
            const int st = (ks * 4 + kq) ^ (rr & (CPR - 1));
            bf16x8 af[4], bfr[4];
#pragma unroll
            for (int mi = 0; mi < 4; ++mi)
                af[mi] = *(const bf16x8*)(ldsA + (wr * 64 + mi * 16 + rr) * BK + st * 8);
#pragma unroll
            for (int ni = 0; ni < 4; ++ni)
                bfr[ni] = *(const bf16x8*)(ldsB + (wc * 64 + ni * 16 + rr) * BK + st * 8);
#pragma unroll
            for (int mi = 0; mi < 4; ++mi)
#pragma unroll
                for (int ni = 0; ni < 4; ++ni)
                    acc[mi][ni] = __builtin_amdgcn_mfma_f32_16x16x32_bf16(af[mi], bfr[ni], acc[mi][ni], 0, 0, 0);
        }
    }

    // Epilogue. C/D layout: col = lane&15, row = (lane>>4)*4 + reg  (m89/m91)
    const long zC = (long)z * sC;
    const int colb = bx * 128 + wc * 64 + rr;
    const int rowb = by * 128 + wr * 64 + kq * 4;
#pragma unroll
    for (int mi = 0; mi < 4; ++mi) {
#pragma unroll
        for (int ni = 0; ni < 4; ++ni) {
            const int col = colb + ni * 16;
            float bv = 0.0f;
            if constexpr (HAS_BIAS) bv = bias[col];
#pragma unroll
            for (int r = 0; r < 4; ++r) {
                const int row = rowb + mi * 16 + r;
                float v = acc[mi][ni][r] * scale + bv;
                if constexpr (EXPW) v = __expf(v - 16.0f);
                if constexpr (ROWSCALE) v *= rowinv[(long)z * sR + row];
                if constexpr (HAS_RESID) v += b2f(resid[(long)z * sR + (long)row * ldr + col]);
                if constexpr (RELU) v = v > 0.0f ? v : 0.0f;
                Cv[zC + (long)row * ldc + col] = f2b(v);
            }
        }
    }
}

// --------------------------- cast f32 -> bf16 ------------------------------
__global__ void cast_f32_bf16(const float* __restrict__ in, unsigned short* __restrict__ out, long n) {
    long i = ((long)blockIdx.x * 256 + threadIdx.x) * 4;
    if (i >= n) return;
    float4 v = *(const float4*)(in + i);
    ushort4 o;
    o.x = f2b(v.x); o.y = f2b(v.y); o.z = f2b(v.z); o.w = f2b(v.w);
    *(ushort4*)(out + i) = o;
}

// --------------------------- concat 3 bias vectors -------------------------
__global__ void concat3(const float* __restrict__ a, const float* __restrict__ b,
                        const float* __restrict__ c, float* __restrict__ o, int n) {
    int i = blockIdx.x * 256 + threadIdx.x;
    if (i < n) { o[i] = a[i]; o[i + n] = b[i]; o[i + 2 * n] = c[i]; }
}

// ------------------- transpose + cast f32[R][C] -> bf16[C][R] --------------
__global__ void transpose_cast(const float* __restrict__ src, unsigned short* __restrict__ dst,
                               int R, int C) {
    __shared__ float tile[32][33];
    const int bx = blockIdx.x * 32;  // col base in src
    const int by = blockIdx.y * 32;  // row base in src
    const int tx = threadIdx.x, ty = threadIdx.y;
#pragma unroll
    for (int i = 0; i < 32; i += 8)
        tile[ty + i][tx] = src[(long)(by + ty + i) * C + bx + tx];
    __syncthreads();
#pragma unroll
    for (int i = 0; i < 32; i += 8)
        dst[(long)(bx + ty + i) * R + by + tx] = f2b(tile[tx][ty + i]);
}

// ------ batched: 4 square f32[N][N] -> bf16[N][N]^T, dst contiguous --------
__global__ void transpose_cast4(const float* __restrict__ s0, const float* __restrict__ s1,
                                const float* __restrict__ s2, const float* __restrict__ s3,
                                unsigned short* __restrict__ dst, int N) {
    const float* src = (blockIdx.z == 0) ? s0 : (blockIdx.z == 1) ? s1 : (blockIdx.z == 2) ? s2 : s3;
    unsigned short* d = dst + (long)blockIdx.z * N * N;
    __shared__ float tile[32][33];
    const int bx = blockIdx.x * 32;
    const int by = blockIdx.y * 32;
    const int tx = threadIdx.x, ty = threadIdx.y;
#pragma unroll
    for (int i = 0; i < 32; i += 8)
        tile[ty + i][tx] = src[(long)(by + ty + i) * N + bx + tx];
    __syncthreads();
#pragma unroll
    for (int i = 0; i < 32; i += 8)
        d[(long)(bx + ty + i) * N + by + tx] = f2b(tile[tx][ty + i]);
}

// -------- transpose bf16 [R][C] (row stride ld) -> [C][R], batched ---------
__global__ void transpose_bf16(const unsigned short* __restrict__ src, long sS, int ld,
                               unsigned short* __restrict__ dst, long sD, int R, int C) {
    const int z = blockIdx.z;
    src += (long)z * sS;
    dst += (long)z * sD;
    __shared__ unsigned short tile[32][33];
    const int bx = blockIdx.x * 32;  // col base
    const int by = blockIdx.y * 32;  // row base
    const int tx = threadIdx.x, ty = threadIdx.y;
#pragma unroll
    for (int i = 0; i < 32; i += 8)
        tile[ty + i][tx] = src[(long)(by + ty + i) * ld + bx + tx];
    __syncthreads();
#pragma unroll
    for (int i = 0; i < 32; i += 8)
        dst[(long)(bx + ty + i) * R + by + tx] = tile[tx][ty + i];
}

// ---- rowsum of bf16 matrix rows (2048 cols) -> 1/sum (fp32) per row -------
__global__ void rowsum_inv(const unsigned short* __restrict__ P, float* __restrict__ inv) {
    const long row = blockIdx.x;
    const ushort4* pr = (const ushort4*)(P + row * 2048);
    const int t = threadIdx.x;
    ushort4 a = pr[t];
    ushort4 b = pr[t + 256];
    float s = b2f(a.x) + b2f(a.y) + b2f(a.z) + b2f(a.w)
            + b2f(b.x) + b2f(b.y) + b2f(b.z) + b2f(b.w);
#pragma unroll
    for (int off = 32; off > 0; off >>= 1) s += __shfl_down(s, off);
    __shared__ float red[4];
    if ((t & 63) == 0) red[t >> 6] = s;
    __syncthreads();
    if (t == 0) inv[row] = 1.0f / (red[0] + red[1] + red[2] + red[3]);
}

// ------------------ LayerNorm (1024 cols), bf16 input ----------------------
template <bool OUT_F32>
__global__ void layernorm_bf16(const unsigned short* __restrict__ in, float* outf,
                               unsigned short* outb,
                               const float* __restrict__ g, const float* __restrict__ b) {
    const long row = blockIdx.x;
    const int t = threadIdx.x;
    const ushort4 u = ((const ushort4*)(in + row * 1024))[t];
    float4 v;
    v.x = b2f(u.x); v.y = b2f(u.y); v.z = b2f(u.z); v.w = b2f(u.w);
    float s = v.x + v.y + v.z + v.w;
    float q = v.x * v.x + v.y * v.y + v.z * v.z + v.w * v.w;
#pragma unroll
    for (int off = 32; off > 0; off >>= 1) {
        s += __shfl_down(s, off);
        q += __shfl_down(q, off);
    }
    __shared__ float red[8];
    if ((t & 63) == 0) { red[t >> 6] = s; red[4 + (t >> 6)] = q; }
    __syncthreads();
    s = red[0] + red[1] + red[2] + red[3];
    q = red[4] + red[5] + red[6] + red[7];
    const float mean = s * (1.0f / 1024.0f);
    const float var  = q * (1.0f / 1024.0f) - mean * mean;
    const float inv  = rsqrtf(var + 1e-5f);
    const float4 gg = ((const float4*)g)[t];
    const float4 bb = ((const float4*)b)[t];
    float4 o;
    o.x = (v.x - mean) * inv * gg.x + bb.x;
    o.y = (v.y - mean) * inv * gg.y + bb.y;
    o.z = (v.z - mean) * inv * gg.z + bb.z;
    o.w = (v.w - mean) * inv * gg.w + bb.w;
    if constexpr (OUT_F32) {
        ((float4*)(outf + row * 1024))[t] = o;
    } else {
        ushort4 ob;
        ob.x = f2b(o.x); ob.y = f2b(o.y); ob.z = f2b(o.z); ob.w = f2b(o.w);
        ((ushort4*)(outb + row * 1024))[t] = ob;
    }
}

// ---------------------------------------------------------------------------
extern "C" void kernel_launch(void* const* d_in, const int* in_sizes, int n_in,
                              void* d_out, int out_size, void* d_ws, size_t ws_size,
                              hipStream_t stream) {
    (void)in_sizes; (void)n_in; (void)out_size; (void)ws_size;
    const float* x   = (const float*)d_in[0];
    const float* wq  = (const float*)d_in[1];
    const float* bq  = (const float*)d_in[2];
    const float* wk  = (const float*)d_in[3];
    const float* bk  = (const float*)d_in[4];
    const float* wv  = (const float*)d_in[5];
    const float* bv  = (const float*)d_in[6];
    const float* wo  = (const float*)d_in[7];
    const float* bo  = (const float*)d_in[8];
    const float* w1  = (const float*)d_in[9];
    const float* b1  = (const float*)d_in[10];
    const float* w2  = (const float*)d_in[11];
    const float* b2  = (const float*)d_in[12];
    const float* g1  = (const float*)d_in[13];
    const float* be1 = (const float*)d_in[14];
    const float* g2  = (const float*)d_in[15];
    const float* be2 = (const float*)d_in[16];

    const int D = 1024, FF = 4096, T = 2048, M = 8192;
    const size_t MB = 1ull << 20;
    char* w = (char*)d_ws;
    // Arena (lifetime-aliased):
    unsigned short* wqT = (unsigned short*)(w + 0 * MB);    // [3072][1024] wcat (wq|wk|wv)
    unsigned short* woT = (unsigned short*)(w + 6 * MB);    // [1024][1024]
    unsigned short* w1T = (unsigned short*)(w + 8 * MB);    // [4096][1024]
    unsigned short* w2T = (unsigned short*)(w + 16 * MB);   // [1024][4096]
    unsigned short* xb  = (unsigned short*)(w + 24 * MB);   // [8192][1024] (QKV A + oproj resid)
    unsigned short* qkv = (unsigned short*)(w + 40 * MB);   // [8192][3072], dead after ctx
    float*          rsum = (float*)(w + 40 * MB);           // [8192] — aliases dead q-part after scores
    float*          bcat = (float*)(w + 88 * MB);           // [3072] — dead before vT written
    unsigned short* vT  = (unsigned short*)(w + 88 * MB);   // [4][1024][2048] (16 MiB), dead after ctx
    unsigned short* pr  = (unsigned short*)(w + 104 * MB);  // [4][2048][2048] bf16 (32 MiB), dead after ctx
    unsigned short* ctxb = (unsigned short*)(w + 136 * MB); // [8192][1024] bf16, dead after oproj
    unsigned short* t0  = (unsigned short*)(w + 152 * MB);  // [8192][1024] bf16 (16 MiB), dead after LN1
    unsigned short* x1b = (unsigned short*)(w + 56 * MB);   // [8192][1024] bf16 (FFN1 A + FFN2 resid)
    unsigned short* h   = (unsigned short*)(w + 88 * MB);   // [8192][4096] bf16 (64 MiB), reuse vT/pr/ctxb
    unsigned short* y   = (unsigned short*)(w + 168 * MB);  // [8192][1024] bf16 (16 MiB)

    const dim3 tb(32, 8);
    // weight transposes + casts (wq/wk/wv/wo batched; dst contiguous from wqT)
    transpose_cast4<<<dim3(32, 32, 4), tb, 0, stream>>>(wq, wk, wv, wo, wqT, D);
    transpose_cast<<<dim3(128, 32), tb, 0, stream>>>(w1, w1T, D, FF);
    transpose_cast<<<dim3(32, 128), tb, 0, stream>>>(w2, w2T, FF, D);
    concat3<<<4, 256, 0, stream>>>(bq, bk, bv, bcat, D);
    cast_f32_bf16<<<8192, 256, 0, stream>>>(x, xb, (long)M * D);

    // Fused QKV projection: [8192][3072] = xb @ wcat^T + bcat
    gemm_bt<0, 64><<<dim3(24, 64, 1), 256, 0, stream>>>(xb, D, wqT, D, qkv, 3 * D, bcat, nullptr, 0,
                                                        nullptr, M, 3 * D, D, 0, 0, 0, 0, 1.0f);

    // V transpose per batch: view [2048][1024] (stride 3072) -> [1024][2048]
    transpose_bf16<<<dim3(32, 64, 4), tb, 0, stream>>>(qkv + 2 * D, (long)T * 3 * D, 3 * D,
                                                       vT, (long)D * T, T, D);

    // P = exp(q @ k^T / sqrt(128) - 16), bf16 unnormalized
    gemm_bt<1, 64><<<dim3(16, 16, 4), 256, 0, stream>>>(qkv, 3 * D, qkv + D, 3 * D, pr, T,
                                                        nullptr, nullptr, 0, nullptr, T, T, D,
                                                        (long)T * 3 * D, (long)T * 3 * D, (long)T * T, 0,
                                                        0.08838834764831845f);
    // 1/rowsum (q-part of qkv dead now; rsum aliases it)
    rowsum_inv<<<8192, 256, 0, stream>>>(pr, rsum);

    // ctx = (P @ v) * rowinv   (512 blocks = 2/CU -> BK=128 is free)
    gemm_bt<2, 128><<<dim3(8, 16, 4), 256, 0, stream>>>(pr, T, vT, T, ctxb, D,
                                                        nullptr, nullptr, 0, rsum, T, D, T,
                                                        (long)T * T, (long)D * T, (long)T * D, T, 1.0f);

    // o-projection + residual (bf16 xb), bf16 out  (512 blocks -> BK=128)
    gemm_bt<3, 128><<<dim3(8, 64, 1), 256, 0, stream>>>(ctxb, D, woT, D, t0, D, bo, xb, D,
                                                        nullptr, M, D, D, 0, 0, 0, 0, 1.0f);

    // LN1 (bf16 in) -> bf16 x1b (FFN input + FFN2 residual)
    layernorm_bf16<false><<<8192, 256, 0, stream>>>(t0, nullptr, x1b, g1, be1);

    // FFN1 (2048 blocks -> keep BK=64 for occupancy)
    gemm_bt<4, 64><<<dim3(32, 64, 1), 256, 0, stream>>>(x1b, D, w1T, D, h, FF, b1, nullptr, 0,
                                                        nullptr, M, FF, D, 0, 0, 0, 0, 1.0f);
    // FFN2 (512 blocks -> BK=128)
    gemm_bt<3, 128><<<dim3(8, 64, 1), 256, 0, stream>>>(h, FF, w2T, FF, y, D, b2, x1b, D,
                                                        nullptr, M, D, FF, 0, 0, 0, 0, 1.0f);

    // LN2 (bf16 in) -> output (fp32)
    layernorm_bf16<true><<<8192, 256, 0, stream>>>(y, (float*)d_out, nullptr, g2, be2);
}